// Round 2
// baseline (107.886 us; speedup 1.0000x reference)
//
#include <hip/hip_runtime.h>
#include <hip/hip_bf16.h>
#include <stdint.h>

typedef __bf16 v8bf __attribute__((ext_vector_type(8)));
typedef float  v4f  __attribute__((ext_vector_type(4)));

#define LEAK 0.2f

static __device__ __forceinline__ unsigned short bf16rne(float f) {
    union { float f; uint32_t u; } v; v.f = f;
    return (unsigned short)((v.u + 0x7FFFu + ((v.u >> 16) & 1u)) >> 16);
}

// ---------------------------------------------------------------------------
// K0: Wt[c][i] = bf16(W[i][c]),  W:[64][3840] f32,  Wt:[3840][64] bf16
// ---------------------------------------------------------------------------
__global__ __launch_bounds__(256) void k0_wt(const float* __restrict__ W,
                                             unsigned short* __restrict__ Wt) {
    __shared__ float tile[64][65];
    const int c0 = blockIdx.x * 64;      // 60 blocks
    const int t  = threadIdx.x;
    {
        const int cl = t & 63, ig = t >> 6;
#pragma unroll
        for (int r = 0; r < 16; ++r) {
            int i = ig + (r << 2);
            tile[i][cl] = W[i * 3840 + c0 + cl];
        }
    }
    __syncthreads();
    {
        const int il = t & 63, cg = t >> 6;
#pragma unroll
        for (int r = 0; r < 16; ++r) {
            int c = cg + (r << 2);
            Wt[(c0 + c) * 64 + il] = bf16rne(tile[il][c]);
        }
    }
}

// ---------------------------------------------------------------------------
// K1: Yt[j][n*60+lt] = bf16( sum_i x[n,i] * W[i, c=j*60+lt] )
// ---------------------------------------------------------------------------
__global__ __launch_bounds__(256) void k1_ygemm(const float* __restrict__ x,
                                                const unsigned short* __restrict__ Wt,
                                                unsigned short* __restrict__ Yt) {
    __shared__ unsigned short As[64 * 64];
    __shared__ unsigned short Bs[64 * 64];
    const int blk = blockIdx.x;
    const int nt = blk / 60, ct = blk % 60;
    const int n0 = nt * 64, c0 = ct * 64;
    const int t = threadIdx.x;
    char* const asb = (char*)As;
    char* const bsb = (char*)Bs;

#pragma unroll
    for (int r = 0; r < 4; ++r) {
        const int rr = (t >> 4) + (r << 4);
        const int cq = t & 15;
        const float4 v = *reinterpret_cast<const float4*>(x + (n0 + rr) * 64 + cq * 4);
        uint2 p;
        p.x = (uint32_t)bf16rne(v.x) | ((uint32_t)bf16rne(v.y) << 16);
        p.y = (uint32_t)bf16rne(v.z) | ((uint32_t)bf16rne(v.w) << 16);
        const int off = rr * 128 + ((cq * 8) ^ ((rr & 7) << 4));
        *reinterpret_cast<uint2*>(asb + off) = p;
    }
#pragma unroll
    for (int r = 0; r < 2; ++r) {
        const int chunk = t + (r << 8);
        const int row = chunk >> 3, c16 = chunk & 7;
        const uint4 v = *reinterpret_cast<const uint4*>(Wt + (c0 + row) * 64 + c16 * 8);
        const int off = row * 128 + ((c16 * 16) ^ ((row & 7) << 4));
        *reinterpret_cast<uint4*>(bsb + off) = v;
    }
    __syncthreads();

    const int w = t >> 6, l = t & 63;
    v4f acc[4];
#pragma unroll
    for (int jt = 0; jt < 4; ++jt) acc[jt] = (v4f){0.f, 0.f, 0.f, 0.f};

#pragma unroll
    for (int s = 0; s < 2; ++s) {
        const int ar = 16 * w + (l & 15);
        const v8bf af = *reinterpret_cast<const v8bf*>(
            asb + ar * 128 + ((64 * s + (l >> 4) * 16) ^ ((ar & 7) << 4)));
#pragma unroll
        for (int jt = 0; jt < 4; ++jt) {
            const int br = 16 * jt + (l & 15);
            const v8bf bf = *reinterpret_cast<const v8bf*>(
                bsb + br * 128 + ((64 * s + (l >> 4) * 16) ^ ((br & 7) << 4)));
            acc[jt] = __builtin_amdgcn_mfma_f32_16x16x32_bf16(af, bf, acc[jt], 0, 0, 0);
        }
    }

#pragma unroll
    for (int jt = 0; jt < 4; ++jt) {
#pragma unroll
        for (int r = 0; r < 4; ++r) {
            const int n = n0 + 16 * w + (l >> 4) * 4 + r;
            const int c = c0 + jt * 16 + (l & 15);
            const int j = c / 60, lt = c % 60;
            Yt[j * 61440 + n * 60 + lt] = bf16rne(acc[jt][r]);
        }
    }
}

// ---------------------------------------------------------------------------
// K2: split-K main GEMM, LDS-FREE streaming version.
// partial[ks][m][j] = sum_{k in 960-chunk} adj[m][k] * Yt[j][k]
// grid 1024 = 16 m-tiles * 64 k-splits, 256 threads (4 waves).
// Each lane loads its own MFMA fragments directly:
//   A: adj row (m0+16w+(l&15)), k-chunk (l>>4)*8 (+32 for ss=1), f32 -> cvt bf16
//   B: Yt row (16jt+(l&15)),    same k-chunk, bf16 16B loads (L2-resident)
// Per-quarter-wave the 4 k-chunk groups complete 256B/row (A) and 128B/row (B)
// -> full cacheline consumption. No barriers, no LDS: pure latency-hidden
// streaming of adj at HBM rate.
// ---------------------------------------------------------------------------
__global__ __launch_bounds__(256) void k2_main(const float* __restrict__ adj,
                                               const unsigned short* __restrict__ Yt,
                                               float* __restrict__ partial) {
    const int blk = blockIdx.x;
    const int mt = blk >> 6, ks = blk & 63;
    const int m0 = mt * 64;
    const int t = threadIdx.x;
    const int w = t >> 6, l = t & 63;
    const int lr = l & 15, lg = l >> 4;
    const long kc0 = (long)ks * 960;

    const float* pa = adj + (size_t)(m0 + 16 * w + lr) * 61440 + kc0 + lg * 8;
    const unsigned short* pb0 = Yt + (size_t)(lr)*61440 + kc0 + lg * 8;
    const unsigned short* pb1 = pb0 + (size_t)16 * 61440;
    const unsigned short* pb2 = pb0 + (size_t)32 * 61440;
    const unsigned short* pb3 = pb0 + (size_t)48 * 61440;

    v4f acc[4];
#pragma unroll
    for (int jt = 0; jt < 4; ++jt) acc[jt] = (v4f){0.f, 0.f, 0.f, 0.f};

#pragma unroll 3
    for (int s = 0; s < 15; ++s) {
        const float* a = pa + s * 64;
        // A fragments (f32 -> bf16)
        v8bf af[2];
#pragma unroll
        for (int ss = 0; ss < 2; ++ss) {
            const float4 x0 = *reinterpret_cast<const float4*>(a + ss * 32);
            const float4 x1 = *reinterpret_cast<const float4*>(a + ss * 32 + 4);
            v8bf f;
            f[0] = (__bf16)x0.x; f[1] = (__bf16)x0.y;
            f[2] = (__bf16)x0.z; f[3] = (__bf16)x0.w;
            f[4] = (__bf16)x1.x; f[5] = (__bf16)x1.y;
            f[6] = (__bf16)x1.z; f[7] = (__bf16)x1.w;
            af[ss] = f;
        }
        // B fragments (bf16 direct)
        const v8bf b00 = *reinterpret_cast<const v8bf*>(pb0 + s * 64);
        const v8bf b01 = *reinterpret_cast<const v8bf*>(pb0 + s * 64 + 32);
        const v8bf b10 = *reinterpret_cast<const v8bf*>(pb1 + s * 64);
        const v8bf b11 = *reinterpret_cast<const v8bf*>(pb1 + s * 64 + 32);
        const v8bf b20 = *reinterpret_cast<const v8bf*>(pb2 + s * 64);
        const v8bf b21 = *reinterpret_cast<const v8bf*>(pb2 + s * 64 + 32);
        const v8bf b30 = *reinterpret_cast<const v8bf*>(pb3 + s * 64);
        const v8bf b31 = *reinterpret_cast<const v8bf*>(pb3 + s * 64 + 32);

        acc[0] = __builtin_amdgcn_mfma_f32_16x16x32_bf16(af[0], b00, acc[0], 0, 0, 0);
        acc[1] = __builtin_amdgcn_mfma_f32_16x16x32_bf16(af[0], b10, acc[1], 0, 0, 0);
        acc[2] = __builtin_amdgcn_mfma_f32_16x16x32_bf16(af[0], b20, acc[2], 0, 0, 0);
        acc[3] = __builtin_amdgcn_mfma_f32_16x16x32_bf16(af[0], b30, acc[3], 0, 0, 0);
        acc[0] = __builtin_amdgcn_mfma_f32_16x16x32_bf16(af[1], b01, acc[0], 0, 0, 0);
        acc[1] = __builtin_amdgcn_mfma_f32_16x16x32_bf16(af[1], b11, acc[1], 0, 0, 0);
        acc[2] = __builtin_amdgcn_mfma_f32_16x16x32_bf16(af[1], b21, acc[2], 0, 0, 0);
        acc[3] = __builtin_amdgcn_mfma_f32_16x16x32_bf16(af[1], b31, acc[3], 0, 0, 0);
    }

    float* const p = partial + (long)ks * 65536;
#pragma unroll
    for (int jt = 0; jt < 4; ++jt) {
#pragma unroll
        for (int r = 0; r < 4; ++r) {
            const int m = m0 + 16 * w + lg * 4 + r;
            const int j = jt * 16 + lr;
            p[m * 64 + j] = acc[jt][r];
        }
    }
}

// ---------------------------------------------------------------------------
// K3: out = lrelu( sum_splits partial + x @ W2 )
// ---------------------------------------------------------------------------
__global__ __launch_bounds__(256) void k3_epi(const float* __restrict__ partial,
                                              const float* __restrict__ x,
                                              const float* __restrict__ W2,
                                              float* __restrict__ out) {
    const int idx = blockIdx.x * 256 + threadIdx.x;   // 0..65535
    const int m = idx >> 6, j = idx & 63;
    float s = 0.f;
#pragma unroll 8
    for (int sp = 0; sp < 64; ++sp) s += partial[sp * 65536 + idx];
    float sk = 0.f;
#pragma unroll 8
    for (int i = 0; i < 64; ++i) sk += x[m * 64 + i] * W2[i * 64 + j];
    const float v = s + sk;
    out[idx] = fmaxf(v, LEAK * v);
}

// ---------------------------------------------------------------------------
extern "C" void kernel_launch(void* const* d_in, const int* in_sizes, int n_in,
                              void* d_out, int out_size, void* d_ws, size_t ws_size,
                              hipStream_t stream) {
    const float* x   = (const float*)d_in[0];
    const float* adj = (const float*)d_in[1];
    const float* W   = (const float*)d_in[2];
    const float* W2  = (const float*)d_in[3];
    float* out = (float*)d_out;

    char* ws = (char*)d_ws;
    unsigned short* Wt = (unsigned short*)ws;                  // 491,520 B
    unsigned short* Yt = (unsigned short*)(ws + 524288);       // 7,864,320 B
    float* partial     = (float*)(ws + 8388608);               // 16,777,216 B

    k0_wt   <<<60,   256, 0, stream>>>(W, Wt);
    k1_ygemm<<<960,  256, 0, stream>>>(x, Wt, Yt);
    k2_main <<<1024, 256, 0, stream>>>(adj, Yt, partial);
    k3_epi  <<<256,  256, 0, stream>>>(partial, x, W2, out);
}

// Round 3
// 59.506 us; speedup vs baseline: 1.8130x; 1.8130x over previous
//
#include <hip/hip_runtime.h>
#include <hip/hip_bf16.h>
#include <stdint.h>

typedef __bf16 v8bf __attribute__((ext_vector_type(8)));
typedef float  v4f  __attribute__((ext_vector_type(4)));

#define LEAK 0.2f

static __device__ __forceinline__ unsigned short bf16rne(float f) {
    union { float f; uint32_t u; } v; v.f = f;
    return (unsigned short)((v.u + 0x7FFFu + ((v.u >> 16) & 1u)) >> 16);
}

static __device__ __forceinline__ void gload16(const void* g, void* l) {
    __builtin_amdgcn_global_load_lds(
        (const __attribute__((address_space(1))) void*)g,
        (__attribute__((address_space(3))) void*)l, 16, 0, 0);
}

// ---------------------------------------------------------------------------
// K0: Wt[c][i] = bf16(W[i][c]),  W:[64][3840] f32,  Wt:[3840][64] bf16
// ---------------------------------------------------------------------------
__global__ __launch_bounds__(256) void k0_wt(const float* __restrict__ W,
                                             unsigned short* __restrict__ Wt) {
    __shared__ float tile[64][65];
    const int c0 = blockIdx.x * 64;      // 60 blocks
    const int t  = threadIdx.x;
    {
        const int cl = t & 63, ig = t >> 6;
#pragma unroll
        for (int r = 0; r < 16; ++r) {
            int i = ig + (r << 2);
            tile[i][cl] = W[i * 3840 + c0 + cl];
        }
    }
    __syncthreads();
    {
        const int il = t & 63, cg = t >> 6;
#pragma unroll
        for (int r = 0; r < 16; ++r) {
            int c = cg + (r << 2);
            Wt[(c0 + c) * 64 + il] = bf16rne(tile[il][c]);
        }
    }
}

// ---------------------------------------------------------------------------
// K1: Yt[j][n*60+lt] = bf16( sum_i x[n,i] * W[i, c=j*60+lt] )
// ---------------------------------------------------------------------------
__global__ __launch_bounds__(256) void k1_ygemm(const float* __restrict__ x,
                                                const unsigned short* __restrict__ Wt,
                                                unsigned short* __restrict__ Yt) {
    __shared__ unsigned short As[64 * 64];
    __shared__ unsigned short Bs[64 * 64];
    const int blk = blockIdx.x;
    const int nt = blk / 60, ct = blk % 60;
    const int n0 = nt * 64, c0 = ct * 64;
    const int t = threadIdx.x;
    char* const asb = (char*)As;
    char* const bsb = (char*)Bs;

#pragma unroll
    for (int r = 0; r < 4; ++r) {
        const int rr = (t >> 4) + (r << 4);
        const int cq = t & 15;
        const float4 v = *reinterpret_cast<const float4*>(x + (n0 + rr) * 64 + cq * 4);
        uint2 p;
        p.x = (uint32_t)bf16rne(v.x) | ((uint32_t)bf16rne(v.y) << 16);
        p.y = (uint32_t)bf16rne(v.z) | ((uint32_t)bf16rne(v.w) << 16);
        const int off = rr * 128 + ((cq * 8) ^ ((rr & 7) << 4));
        *reinterpret_cast<uint2*>(asb + off) = p;
    }
#pragma unroll
    for (int r = 0; r < 2; ++r) {
        const int chunk = t + (r << 8);
        const int row = chunk >> 3, c16 = chunk & 7;
        const uint4 v = *reinterpret_cast<const uint4*>(Wt + (c0 + row) * 64 + c16 * 8);
        const int off = row * 128 + ((c16 * 16) ^ ((row & 7) << 4));
        *reinterpret_cast<uint4*>(bsb + off) = v;
    }
    __syncthreads();

    const int w = t >> 6, l = t & 63;
    v4f acc[4];
#pragma unroll
    for (int jt = 0; jt < 4; ++jt) acc[jt] = (v4f){0.f, 0.f, 0.f, 0.f};

#pragma unroll
    for (int s = 0; s < 2; ++s) {
        const int ar = 16 * w + (l & 15);
        const v8bf af = *reinterpret_cast<const v8bf*>(
            asb + ar * 128 + ((64 * s + (l >> 4) * 16) ^ ((ar & 7) << 4)));
#pragma unroll
        for (int jt = 0; jt < 4; ++jt) {
            const int br = 16 * jt + (l & 15);
            const v8bf bf = *reinterpret_cast<const v8bf*>(
                bsb + br * 128 + ((64 * s + (l >> 4) * 16) ^ ((br & 7) << 4)));
            acc[jt] = __builtin_amdgcn_mfma_f32_16x16x32_bf16(af, bf, acc[jt], 0, 0, 0);
        }
    }

#pragma unroll
    for (int jt = 0; jt < 4; ++jt) {
#pragma unroll
        for (int r = 0; r < 4; ++r) {
            const int n = n0 + 16 * w + (l >> 4) * 4 + r;
            const int c = c0 + jt * 16 + (l & 15);
            const int j = c / 60, lt = c % 60;
            Yt[j * 61440 + n * 60 + lt] = bf16rne(acc[jt][r]);
        }
    }
}

// ---------------------------------------------------------------------------
// K2: split-K GEMM with global_load_lds DMA staging + 3-buffer 2-deep
// counted-vmcnt pipeline (1 raw s_barrier / K-step, never vmcnt(0) in loop).
// partial[ks][m][j] = sum_{k in 1920-chunk} adj[m][k]*Yt[j][k]
// grid 512 = 16 m-tiles * 32 k-splits, 256 threads (4 waves), 30 BK=64 steps.
// LDS per buffer: A f32 64x64 (16KB, 256B rows) + B bf16 64x64 (8KB, 128B
// rows); 3 buffers = 72KB. Swizzle (rule 21): linear LDS dest, global source
// offset XOR ((row&7)<<4), ds_read at same XOR -> <=2-way bank conflicts.
// ---------------------------------------------------------------------------
__global__ __launch_bounds__(256) void k2_main(const float* __restrict__ adj,
                                               const unsigned short* __restrict__ Yt,
                                               float* __restrict__ partial) {
    __shared__ __align__(16) char lds[73728];
    const int blk = blockIdx.x;
    const int mt = blk >> 5, ks = blk & 31;      // blk%8 == ks%8 -> Yt XCD locality
    const int m0 = mt * 64;
    const long kc0 = (long)ks * 1920;
    const int t = threadIdx.x;
    const int w = t >> 6, l = t & 63;
    const int lr = l & 15, lg = l >> 4;

    // staging source pointers (pre-swizzled within each row)
    const char* srcA[4];
    const char* srcB[2];
#pragma unroll
    for (int k = 0; k < 4; ++k) {
        const int row = k * 16 + w * 4 + lg;
        srcA[k] = (const char*)(adj + (size_t)(m0 + row) * 61440 + kc0)
                  + ((lr * 16) ^ ((row & 7) << 4));
    }
#pragma unroll
    for (int k = 0; k < 2; ++k) {
        const int row = k * 32 + w * 8 + (l >> 3);
        srcB[k] = (const char*)(Yt + (size_t)row * 61440 + kc0)
                  + (((l & 7) * 16) ^ ((row & 7) << 4));
    }

#define STAGE(bs, s) do {                                                      \
        char* ab_ = lds + (bs) * 16384;                                        \
        char* bb_ = lds + 49152 + (bs) * 8192;                                 \
        _Pragma("unroll")                                                      \
        for (int k_ = 0; k_ < 4; ++k_)                                         \
            gload16(srcA[k_] + (size_t)(s) * 256, ab_ + k_ * 4096 + w * 1024); \
        _Pragma("unroll")                                                      \
        for (int k_ = 0; k_ < 2; ++k_)                                         \
            gload16(srcB[k_] + (size_t)(s) * 128, bb_ + k_ * 4096 + w * 1024); \
    } while (0)

    v4f acc[4];
#pragma unroll
    for (int jt = 0; jt < 4; ++jt) acc[jt] = (v4f){0.f, 0.f, 0.f, 0.f};

    const int ar = 16 * w + lr;
    const int sa = (ar & 7) << 4;

    STAGE(0, 0);
    STAGE(1, 1);
    int bs = 2, bc = 0;

#pragma unroll 1
    for (int i = 0; i < 30; ++i) {
        if (i < 29) { asm volatile("s_waitcnt vmcnt(6)" ::: "memory"); }
        else        { asm volatile("s_waitcnt vmcnt(0)" ::: "memory"); }
        __builtin_amdgcn_s_barrier();
        asm volatile("" ::: "memory");
        if (i < 28) STAGE(bs, i + 2);

        const char* ab = lds + bc * 16384;
        const char* bb = lds + 49152 + bc * 8192;
        v8bf af[2];
#pragma unroll
        for (int ss = 0; ss < 2; ++ss) {
            const int Xf = ss * 128 + lg * 32;
            const float4 x0 = *reinterpret_cast<const float4*>(ab + ar * 256 + (Xf ^ sa));
            const float4 x1 = *reinterpret_cast<const float4*>(ab + ar * 256 + ((Xf + 16) ^ sa));
            v8bf f;
            f[0] = (__bf16)x0.x; f[1] = (__bf16)x0.y;
            f[2] = (__bf16)x0.z; f[3] = (__bf16)x0.w;
            f[4] = (__bf16)x1.x; f[5] = (__bf16)x1.y;
            f[6] = (__bf16)x1.z; f[7] = (__bf16)x1.w;
            af[ss] = f;
        }
#pragma unroll
        for (int jt = 0; jt < 4; ++jt) {
            const int br = 16 * jt + lr;
            const int sb = (br & 7) << 4;
            const v8bf b0 = *reinterpret_cast<const v8bf*>(bb + br * 128 + ((lg * 16) ^ sb));
            const v8bf b1 = *reinterpret_cast<const v8bf*>(bb + br * 128 + ((64 + lg * 16) ^ sb));
            acc[jt] = __builtin_amdgcn_mfma_f32_16x16x32_bf16(af[0], b0, acc[jt], 0, 0, 0);
            acc[jt] = __builtin_amdgcn_mfma_f32_16x16x32_bf16(af[1], b1, acc[jt], 0, 0, 0);
        }

        bs = (bs == 2) ? 0 : bs + 1;
        bc = (bc == 2) ? 0 : bc + 1;
    }
#undef STAGE

    float* const p = partial + (long)ks * 65536;
#pragma unroll
    for (int jt = 0; jt < 4; ++jt) {
#pragma unroll
        for (int r = 0; r < 4; ++r) {
            const int m = m0 + 16 * w + lg * 4 + r;
            const int j = jt * 16 + lr;
            p[m * 64 + j] = acc[jt][r];
        }
    }
}

// ---------------------------------------------------------------------------
// K3: out = lrelu( sum_splits partial + x @ W2 )
// ---------------------------------------------------------------------------
__global__ __launch_bounds__(256) void k3_epi(const float* __restrict__ partial,
                                              const float* __restrict__ x,
                                              const float* __restrict__ W2,
                                              float* __restrict__ out) {
    const int idx = blockIdx.x * 256 + threadIdx.x;   // 0..65535
    const int m = idx >> 6, j = idx & 63;
    float s = 0.f;
#pragma unroll 8
    for (int sp = 0; sp < 32; ++sp) s += partial[sp * 65536 + idx];
    float sk = 0.f;
#pragma unroll 8
    for (int i = 0; i < 64; ++i) sk += x[m * 64 + i] * W2[i * 64 + j];
    const float v = s + sk;
    out[idx] = fmaxf(v, LEAK * v);
}

// ---------------------------------------------------------------------------
extern "C" void kernel_launch(void* const* d_in, const int* in_sizes, int n_in,
                              void* d_out, int out_size, void* d_ws, size_t ws_size,
                              hipStream_t stream) {
    const float* x   = (const float*)d_in[0];
    const float* adj = (const float*)d_in[1];
    const float* W   = (const float*)d_in[2];
    const float* W2  = (const float*)d_in[3];
    float* out = (float*)d_out;

    char* ws = (char*)d_ws;
    unsigned short* Wt = (unsigned short*)ws;                  // 491,520 B
    unsigned short* Yt = (unsigned short*)(ws + 524288);       // 7,864,320 B
    float* partial     = (float*)(ws + 8388608);               // 8,388,608 B (32 splits)

    k0_wt   <<<60,  256, 0, stream>>>(W, Wt);
    k1_ygemm<<<960, 256, 0, stream>>>(x, Wt, Yt);
    k2_main <<<512, 256, 0, stream>>>(adj, Yt, partial);
    k3_epi  <<<256, 256, 0, stream>>>(partial, x, W2, out);
}